// Round 4
// baseline (1290.178 us; speedup 1.0000x reference)
//
#include <hip/hip_runtime.h>
#include <math.h>

#define BATCH 2048
#define CIN 14
#define LEN 2048
#define NB 4
#define HID 64
#define NEG 0.01f

// fast activations (f32, ~2ulp via v_exp_f32)
__device__ __forceinline__ float sigm_f(float x) { return 1.0f / (1.0f + __expf(-x)); }
__device__ __forceinline__ float tanh_f(float x) { return 1.0f - 2.0f / (1.0f + __expf(2.0f * x)); }

// ---------------- Kernel A: pool (hierarchical) + conv1d(k=3,pad=1) + LeakyReLU ----------------
// writes xc[bin] in layout [b][t][4] at float offsets base[bin] + b*T*4

__device__ __forceinline__ void conv_bin(const float* __restrict__ P, int ldp, int T,
                                         int bin,
                                         const float* __restrict__ cw,
                                         const float* __restrict__ cb,
                                         float* __restrict__ dst, int tid)
{
    const float* w = cw + (size_t)bin * 4 * CIN * 3;   // w[(f*CIN+ci)*3 + k]
    const float b0 = cb[bin * 4 + 0];
    const float b1 = cb[bin * 4 + 1];
    const float b2 = cb[bin * 4 + 2];
    const float b3 = cb[bin * 4 + 3];
    for (int t = tid; t < T; t += 256) {
        float a0 = b0, a1 = b1, a2 = b2, a3 = b3;
        for (int ci = 0; ci < CIN; ++ci) {
            float pm = (t > 0)     ? P[ci * ldp + t - 1] : 0.0f;
            float p0 =               P[ci * ldp + t];
            float pp = (t < T - 1) ? P[ci * ldp + t + 1] : 0.0f;
            const float* w0 = w + (0 * CIN + ci) * 3;
            const float* w1 = w + (1 * CIN + ci) * 3;
            const float* w2 = w + (2 * CIN + ci) * 3;
            const float* w3 = w + (3 * CIN + ci) * 3;
            a0 += w0[0] * pm + w0[1] * p0 + w0[2] * pp;
            a1 += w1[0] * pm + w1[1] * p0 + w1[2] * pp;
            a2 += w2[0] * pm + w2[1] * p0 + w2[2] * pp;
            a3 += w3[0] * pm + w3[1] * p0 + w3[2] * pp;
        }
        a0 = (a0 >= 0.0f) ? a0 : NEG * a0;
        a1 = (a1 >= 0.0f) ? a1 : NEG * a1;
        a2 = (a2 >= 0.0f) ? a2 : NEG * a2;
        a3 = (a3 >= 0.0f) ? a3 : NEG * a3;
        *reinterpret_cast<float4*>(dst + (size_t)t * 4) = make_float4(a0, a1, a2, a3);
    }
}

__global__ __launch_bounds__(256) void pool_conv_kernel(
    const float* __restrict__ X, const float* __restrict__ cw,
    const float* __restrict__ cb, float* __restrict__ xc)
{
    __shared__ float Pa[CIN][512];
    __shared__ float Pb[CIN][256];
    const int b = blockIdx.x;
    const int tid = threadIdx.x;

    // pool 2048 -> 512 (kernel == stride == 4), coalesced float4 reads
    for (int idx = tid; idx < CIN * 512; idx += 256) {
        int c = idx >> 9, t = idx & 511;
        const float4 v = *reinterpret_cast<const float4*>(X + ((size_t)b * CIN + c) * LEN + 4 * t);
        Pa[c][t] = 0.25f * (v.x + v.y + v.z + v.w);
    }
    __syncthreads();

    conv_bin(&Pa[0][0], 512, 512, 0, cw, cb, xc + (size_t)b * 512 * 4, tid);
    for (int idx = tid; idx < CIN * 256; idx += 256) {
        int c = idx >> 8, t = idx & 255;
        Pb[c][t] = 0.5f * (Pa[c][2 * t] + Pa[c][2 * t + 1]);
    }
    __syncthreads();

    conv_bin(&Pb[0][0], 256, 256, 1, cw, cb, xc + 4194304 + (size_t)b * 256 * 4, tid);
    for (int idx = tid; idx < CIN * 128; idx += 256) {
        int c = idx >> 7, t = idx & 127;
        Pa[c][t] = 0.5f * (Pb[c][2 * t] + Pb[c][2 * t + 1]);
    }
    __syncthreads();

    conv_bin(&Pa[0][0], 512, 128, 2, cw, cb, xc + 6291456 + (size_t)b * 128 * 4, tid);
    for (int idx = tid; idx < CIN * 64; idx += 256) {
        int c = idx >> 6, t = idx & 63;
        Pb[c][t] = 0.5f * (Pa[c][2 * t] + Pa[c][2 * t + 1]);
    }
    __syncthreads();

    conv_bin(&Pb[0][0], 256, 64, 3, cw, cb, xc + 7340032 + (size_t)b * 64 * 4, tid);
}

// ---------------- Kernel B: LSTM scan + linear head ----------------
// 2048 blocks, 256 threads = 4 waves. Block handles 4 batch elements of one bin.
// Thread j: bg = j>>7 selects batch pair (2bg, 2bg+1); hr = j&127 selects TWO
// gate rows: rowA = hr (i for hr<64, f else), rowB = hr+128 (g for hr<64, o else).
// Both rows' weights (128 floats) are PINNED into arch VGPRs via empty asm so
// the compiler cannot demote them to AGPRs/reloads (round-3 showed VGPR=52).
// Each LDS h-read feeds 2 rows -> 32 ds_read_b128 per thread-step (was 64).
// Activations are branch-free: tanh(x) = 2*sigm(2x)-1 via per-thread constants.

__global__ __launch_bounds__(256) void lstm_kernel(
    const float* __restrict__ xc,
    const float* __restrict__ wih, const float* __restrict__ whh,
    const float* __restrict__ bih, const float* __restrict__ bhh,
    const float* __restrict__ lw, const float* __restrict__ lb,
    float* __restrict__ out)
{
    __shared__ float4 h4[4][16];      // h[batch][64]
    __shared__ float  gl[4][4][64];   // [batch][gate][k]
    __shared__ float4 xs[4][64];      // x window: [batch][step]

    const int tid = threadIdx.x;
    const int bg  = tid >> 7;         // batch pair group (0,1)
    const int hr  = tid & 127;        // half-row
    const int p0  = bg * 2, p1 = bg * 2 + 1;
    const int bin = blockIdx.x >> 9;
    const int b0  = (blockIdx.x & 511) << 2;
    const int Ts[NB] = {512, 256, 128, 64};
    const size_t Bs[NB] = {0, 4194304, 6291456, 7340032};
    const int T = Ts[bin];
    const float* xbase = xc + Bs[bin];

    const int rowA = bin * 256 + hr;         // i (hr<64) or f
    const int rowB = bin * 256 + 128 + hr;   // g (hr<64) or o

    float wA[64], wB[64];
    {
        const float* rA = whh + (size_t)rowA * 64;
        const float* rB = whh + (size_t)rowB * 64;
        #pragma unroll
        for (int q = 0; q < 16; ++q) {
            float4 v = *reinterpret_cast<const float4*>(rA + 4 * q);
            wA[4 * q + 0] = v.x; wA[4 * q + 1] = v.y;
            wA[4 * q + 2] = v.z; wA[4 * q + 3] = v.w;
            float4 u = *reinterpret_cast<const float4*>(rB + 4 * q);
            wB[4 * q + 0] = u.x; wB[4 * q + 1] = u.y;
            wB[4 * q + 2] = u.z; wB[4 * q + 3] = u.w;
        }
        // pin into architectural VGPRs (prevent AGPR demotion / remat)
        #pragma unroll
        for (int k = 0; k < 64; ++k) {
            asm volatile("" : "+v"(wA[k]));
            asm volatile("" : "+v"(wB[k]));
        }
    }
    const float4 wiA = *reinterpret_cast<const float4*>(wih + (size_t)rowA * 4);
    const float4 wiB = *reinterpret_cast<const float4*>(wih + (size_t)rowB * 4);
    const float biasA = bih[rowA] + bhh[rowA];
    const float biasB = bih[rowB] + bhh[rowB];

    // branch-free activation constants for B-row: tanh(x) = 2*sigm(2x)-1
    const float sIn = (hr < 64) ? 2.0f : 1.0f;
    const float m1  = (hr < 64) ? 2.0f : 1.0f;
    const float m0  = (hr < 64) ? -1.0f : 0.0f;
    const int   gA  = hr >> 6;       // 0 (i) or 1 (f); B-gate = 2+gA
    const int   kk  = hr & 63;

    ((float*)h4)[tid] = 0.0f;        // 256 = 4*64
    const int ub = tid >> 6, uk = tid & 63;   // state-update assignment
    float c = 0.0f;
    float h = 0.0f;

    for (int t = 0; t < T; ++t) {
        if ((t & 63) == 0) {
            const int bb = tid >> 6, s = tid & 63;
            xs[bb][s] = *reinterpret_cast<const float4*>(
                xbase + ((size_t)(b0 + bb) * T + t + s) * 4);
        }
        __syncthreads();   // A: h(t-1) + x window published

        const int tw = t & 63;
        float4 x0 = xs[p0][tw];
        float4 x1 = xs[p1][tw];
        float aA0 = biasA, aA1 = biasA, aB0 = biasB, aB1 = biasB;
        aA0 = fmaf(wiA.x, x0.x, aA0); aA0 = fmaf(wiA.y, x0.y, aA0);
        aA0 = fmaf(wiA.z, x0.z, aA0); aA0 = fmaf(wiA.w, x0.w, aA0);
        aA1 = fmaf(wiA.x, x1.x, aA1); aA1 = fmaf(wiA.y, x1.y, aA1);
        aA1 = fmaf(wiA.z, x1.z, aA1); aA1 = fmaf(wiA.w, x1.w, aA1);
        aB0 = fmaf(wiB.x, x0.x, aB0); aB0 = fmaf(wiB.y, x0.y, aB0);
        aB0 = fmaf(wiB.z, x0.z, aB0); aB0 = fmaf(wiB.w, x0.w, aB0);
        aB1 = fmaf(wiB.x, x1.x, aB1); aB1 = fmaf(wiB.y, x1.y, aB1);
        aB1 = fmaf(wiB.z, x1.z, aB1); aB1 = fmaf(wiB.w, x1.w, aB1);

        #pragma unroll
        for (int q = 0; q < 16; ++q) {
            const float4 hv0 = h4[p0][q];
            const float4 hv1 = h4[p1][q];
            aA0 = fmaf(wA[4*q+0], hv0.x, aA0); aB0 = fmaf(wB[4*q+0], hv0.x, aB0);
            aA1 = fmaf(wA[4*q+0], hv1.x, aA1); aB1 = fmaf(wB[4*q+0], hv1.x, aB1);
            aA0 = fmaf(wA[4*q+1], hv0.y, aA0); aB0 = fmaf(wB[4*q+1], hv0.y, aB0);
            aA1 = fmaf(wA[4*q+1], hv1.y, aA1); aB1 = fmaf(wB[4*q+1], hv1.y, aB1);
            aA0 = fmaf(wA[4*q+2], hv0.z, aA0); aB0 = fmaf(wB[4*q+2], hv0.z, aB0);
            aA1 = fmaf(wA[4*q+2], hv1.z, aA1); aB1 = fmaf(wB[4*q+2], hv1.z, aB1);
            aA0 = fmaf(wA[4*q+3], hv0.w, aA0); aB0 = fmaf(wB[4*q+3], hv0.w, aB0);
            aA1 = fmaf(wA[4*q+3], hv1.w, aA1); aB1 = fmaf(wB[4*q+3], hv1.w, aB1);
        }

        // A rows: sigmoid. B rows: tanh (hr<64) or sigmoid, branch-free.
        const float gA0 = sigm_f(aA0);
        const float gA1 = sigm_f(aA1);
        const float gB0 = fmaf(sigm_f(aB0 * sIn), m1, m0);
        const float gB1 = fmaf(sigm_f(aB1 * sIn), m1, m0);
        gl[p0][gA][kk] = gA0;      gl[p1][gA][kk] = gA1;
        gl[p0][2 + gA][kk] = gB0;  gl[p1][2 + gA][kk] = gB1;
        __syncthreads();   // B: gates published

        // state update: thread (ub, uk)
        const float gi = gl[ub][0][uk], gf = gl[ub][1][uk];
        const float gg = gl[ub][2][uk], go = gl[ub][3][uk];
        c = fmaf(gf, c, gi * gg);
        h = go * tanh_f(c);
        ((float*)h4)[ub * 64 + uk] = h;
        // published by barrier A of next iteration
    }

    // linear head: wave ub -> batch b0+ub
    float v = h * lw[bin * HID + uk];
    #pragma unroll
    for (int off = 32; off > 0; off >>= 1) v += __shfl_down(v, off);
    if (uk == 0) out[(size_t)(b0 + ub) * NB + bin] = v + lb[bin];
}

extern "C" void kernel_launch(void* const* d_in, const int* in_sizes, int n_in,
                              void* d_out, int out_size, void* d_ws, size_t ws_size,
                              hipStream_t stream) {
    const float* X   = (const float*)d_in[0];
    const float* cw  = (const float*)d_in[1];
    const float* cb  = (const float*)d_in[2];
    const float* wih = (const float*)d_in[3];
    const float* whh = (const float*)d_in[4];
    const float* bih = (const float*)d_in[5];
    const float* bhh = (const float*)d_in[6];
    const float* lw  = (const float*)d_in[7];
    const float* lb  = (const float*)d_in[8];
    float* out = (float*)d_out;
    float* xc  = (float*)d_ws;   // 7,864,320 floats = 31.5 MB

    pool_conv_kernel<<<BATCH, 256, 0, stream>>>(X, cw, cb, xc);
    lstm_kernel<<<NB * (BATCH / 4), 256, 0, stream>>>(xc, wih, whh, bih, bhh, lw, lb, out);
}

// Round 5
// 632.574 us; speedup vs baseline: 2.0396x; 2.0396x over previous
//
#include <hip/hip_runtime.h>
#include <math.h>

#define BATCH 2048
#define CIN 14
#define LEN 2048
#define NB 4
#define HID 64
#define NEG 0.01f

typedef __attribute__((ext_vector_type(8))) __bf16 bf16x8;
typedef __attribute__((ext_vector_type(4))) short short4v;
typedef __attribute__((ext_vector_type(4))) float f32x4;

// fast activations (f32, ~2ulp via v_exp_f32)
__device__ __forceinline__ float sigm_f(float x) { return 1.0f / (1.0f + __expf(-x)); }
__device__ __forceinline__ float tanh_f(float x) { return 1.0f - 2.0f / (1.0f + __expf(2.0f * x)); }

// ---------------- Kernel A: pool (hierarchical) + conv1d(k=3,pad=1) + LeakyReLU ----------------
// writes xc[bin] in layout [b][t][4] at float offsets base[bin] + b*T*4

__device__ __forceinline__ void conv_bin(const float* __restrict__ P, int ldp, int T,
                                         int bin,
                                         const float* __restrict__ cw,
                                         const float* __restrict__ cb,
                                         float* __restrict__ dst, int tid)
{
    const float* w = cw + (size_t)bin * 4 * CIN * 3;   // w[(f*CIN+ci)*3 + k]
    const float b0 = cb[bin * 4 + 0];
    const float b1 = cb[bin * 4 + 1];
    const float b2 = cb[bin * 4 + 2];
    const float b3 = cb[bin * 4 + 3];
    for (int t = tid; t < T; t += 256) {
        float a0 = b0, a1 = b1, a2 = b2, a3 = b3;
        for (int ci = 0; ci < CIN; ++ci) {
            float pm = (t > 0)     ? P[ci * ldp + t - 1] : 0.0f;
            float p0 =               P[ci * ldp + t];
            float pp = (t < T - 1) ? P[ci * ldp + t + 1] : 0.0f;
            const float* w0 = w + (0 * CIN + ci) * 3;
            const float* w1 = w + (1 * CIN + ci) * 3;
            const float* w2 = w + (2 * CIN + ci) * 3;
            const float* w3 = w + (3 * CIN + ci) * 3;
            a0 += w0[0] * pm + w0[1] * p0 + w0[2] * pp;
            a1 += w1[0] * pm + w1[1] * p0 + w1[2] * pp;
            a2 += w2[0] * pm + w2[1] * p0 + w2[2] * pp;
            a3 += w3[0] * pm + w3[1] * p0 + w3[2] * pp;
        }
        a0 = (a0 >= 0.0f) ? a0 : NEG * a0;
        a1 = (a1 >= 0.0f) ? a1 : NEG * a1;
        a2 = (a2 >= 0.0f) ? a2 : NEG * a2;
        a3 = (a3 >= 0.0f) ? a3 : NEG * a3;
        *reinterpret_cast<float4*>(dst + (size_t)t * 4) = make_float4(a0, a1, a2, a3);
    }
}

__global__ __launch_bounds__(256) void pool_conv_kernel(
    const float* __restrict__ X, const float* __restrict__ cw,
    const float* __restrict__ cb, float* __restrict__ xc)
{
    __shared__ float Pa[CIN][512];
    __shared__ float Pb[CIN][256];
    const int b = blockIdx.x;
    const int tid = threadIdx.x;

    for (int idx = tid; idx < CIN * 512; idx += 256) {
        int c = idx >> 9, t = idx & 511;
        const float4 v = *reinterpret_cast<const float4*>(X + ((size_t)b * CIN + c) * LEN + 4 * t);
        Pa[c][t] = 0.25f * (v.x + v.y + v.z + v.w);
    }
    __syncthreads();

    conv_bin(&Pa[0][0], 512, 512, 0, cw, cb, xc + (size_t)b * 512 * 4, tid);
    for (int idx = tid; idx < CIN * 256; idx += 256) {
        int c = idx >> 8, t = idx & 255;
        Pb[c][t] = 0.5f * (Pa[c][2 * t] + Pa[c][2 * t + 1]);
    }
    __syncthreads();

    conv_bin(&Pb[0][0], 256, 256, 1, cw, cb, xc + 4194304 + (size_t)b * 256 * 4, tid);
    for (int idx = tid; idx < CIN * 128; idx += 256) {
        int c = idx >> 7, t = idx & 127;
        Pa[c][t] = 0.5f * (Pb[c][2 * t] + Pb[c][2 * t + 1]);
    }
    __syncthreads();

    conv_bin(&Pa[0][0], 512, 128, 2, cw, cb, xc + 6291456 + (size_t)b * 128 * 4, tid);
    for (int idx = tid; idx < CIN * 64; idx += 256) {
        int c = idx >> 6, t = idx & 63;
        Pb[c][t] = 0.5f * (Pa[c][2 * t] + Pa[c][2 * t + 1]);
    }
    __syncthreads();

    conv_bin(&Pb[0][0], 256, 64, 3, cw, cb, xc + 7340032 + (size_t)b * 64 * 4, tid);
}

// ---------------- Kernel B: MFMA LSTM scan + linear head ----------------
// 256 blocks x 256 threads (4 waves). Blocks 0..127: bin 0, batch group 16*blockIdx.
// Blocks 128..255: bins 1,2,3 chained (448 steps total) for batch group 16*(blockIdx-128).
// Gates[16 batch][256 cols] via mfma_f32_16x16x32_bf16, split-bf16 (hi/lo) for fp32 accuracy:
//   A = h[16x64] (2 K-tiles), B = Whh^T tiles; x·Wih^T + bias folded into fp32 C-init.
// Wave w owns cols {g*64 + w*16 + (lane&15)} for g=0..3 -> lane holds i,f,g,o for ONE unit
// and 4 batch rows (C/D: col=lane&15, row=(lane>>4)*4+reg) -> in-register c/h update.
// h exchanged per step via LDS bf16 hi/lo planes [16][72] (pad kills bank conflicts).

__global__ __launch_bounds__(256, 1) void lstm_mfma_kernel(
    const float* __restrict__ xc,
    const float* __restrict__ wih, const float* __restrict__ whh,
    const float* __restrict__ bih, const float* __restrict__ bhh,
    const float* __restrict__ lw, const float* __restrict__ lb,
    float* __restrict__ out)
{
    __shared__ float4 xs[16][65];      // x window [batch][step], pad 65 breaks bank aliasing
    __shared__ __bf16 hhi[16][72];     // h high bf16 plane, row pad 72
    __shared__ __bf16 hlo[16][72];     // h residual bf16 plane
    __shared__ float  part[256];       // head reduction

    const int tid = threadIdx.x;
    const int w   = tid >> 6;          // wave id 0..3
    const int l   = tid & 63;          // lane
    const int lm  = l & 15;            // A row / B col / D col
    const int lg  = l >> 4;            // k-group / D row group

    const int TS[NB]     = {512, 256, 128, 64};
    const size_t OFF[NB] = {0, 4194304, 6291456, 7340032};

    const bool isBin0 = (blockIdx.x < 128);
    const int b0   = (isBin0 ? blockIdx.x : (blockIdx.x - 128)) * 16;
    const int binS = isBin0 ? 0 : 1;
    const int binE = isBin0 ? 1 : 4;

    for (int bin = binS; bin < binE; ++bin) {
        const int T = TS[bin];
        const float* xbase = xc + OFF[bin];

        // ---- load + split weights into register fragments (per lane: 64 VGPR) ----
        bf16x8 whiF[4][2], wloF[4][2];
        float4 wi4[4];
        float  bias[4];
        #pragma unroll
        for (int g = 0; g < 4; ++g) {
            const int col = bin * 256 + g * 64 + w * 16 + lm;
            const float* wr = whh + (size_t)col * 64;
            #pragma unroll
            for (int kt = 0; kt < 2; ++kt) {
                const float* p = wr + kt * 32 + lg * 8;
                const float4 u0 = *reinterpret_cast<const float4*>(p);
                const float4 u1 = *reinterpret_cast<const float4*>(p + 4);
                const float v[8] = {u0.x, u0.y, u0.z, u0.w, u1.x, u1.y, u1.z, u1.w};
                bf16x8 hi8, lo8;
                #pragma unroll
                for (int e = 0; e < 8; ++e) {
                    const __bf16 hb = (__bf16)v[e];
                    hi8[e] = hb;
                    lo8[e] = (__bf16)(v[e] - (float)hb);
                }
                whiF[g][kt] = hi8;
                wloF[g][kt] = lo8;
            }
            wi4[g]  = *reinterpret_cast<const float4*>(wih + (size_t)col * 4);
            bias[g] = bih[col] + bhh[col];
        }

        // ---- zero h planes ----
        #pragma unroll
        for (int i = 0; i < 5; ++i) {
            const int idx = tid + i * 256;
            if (idx < 16 * 72) {
                (&hhi[0][0])[idx] = (__bf16)0.0f;
                (&hlo[0][0])[idx] = (__bf16)0.0f;
            }
        }
        float c4[4] = {0.0f, 0.0f, 0.0f, 0.0f};

        for (int t = 0; t < T; ++t) {
            if ((t & 63) == 0) {
                #pragma unroll
                for (int i = 0; i < 4; ++i) {
                    const int idx = tid + i * 256;
                    const int bb = idx >> 6, s = idx & 63;
                    xs[bb][s] = *reinterpret_cast<const float4*>(
                        xbase + ((size_t)(b0 + bb) * T + t + s) * 4);
                }
            }
            __syncthreads();   // A: h(t-1) + x window published

            // A-operand fragments: z[m=lm][k=lg*8+e (+32*kt)]
            bf16x8 zhi[2], zlo[2];
            #pragma unroll
            for (int kt = 0; kt < 2; ++kt) {
                const __bf16* ph = &hhi[lm][kt * 32 + lg * 8];
                const short4v h0 = *reinterpret_cast<const short4v*>(ph);
                const short4v h1 = *reinterpret_cast<const short4v*>(ph + 4);
                zhi[kt] = __builtin_bit_cast(bf16x8,
                          __builtin_shufflevector(h0, h1, 0, 1, 2, 3, 4, 5, 6, 7));
                const __bf16* pl = &hlo[lm][kt * 32 + lg * 8];
                const short4v l0 = *reinterpret_cast<const short4v*>(pl);
                const short4v l1 = *reinterpret_cast<const short4v*>(pl + 4);
                zlo[kt] = __builtin_bit_cast(bf16x8,
                          __builtin_shufflevector(l0, l1, 0, 1, 2, 3, 4, 5, 6, 7));
            }
            const int tw = t & 63;
            float4 x4[4];
            #pragma unroll
            for (int r = 0; r < 4; ++r) x4[r] = xs[lg * 4 + r][tw];
            __syncthreads();   // B: all reads of h(t-1)/xs done

            // gates: C-init (bias + x·Wih^T, fp32) then 6 split-bf16 MFMAs per gate tile
            f32x4 acc[4];
            #pragma unroll
            for (int g = 0; g < 4; ++g) {
                f32x4 a;
                #pragma unroll
                for (int r = 0; r < 4; ++r) {
                    float v = bias[g];
                    v = fmaf(wi4[g].x, x4[r].x, v);
                    v = fmaf(wi4[g].y, x4[r].y, v);
                    v = fmaf(wi4[g].z, x4[r].z, v);
                    v = fmaf(wi4[g].w, x4[r].w, v);
                    a[r] = v;
                }
                a = __builtin_amdgcn_mfma_f32_16x16x32_bf16(zhi[0], whiF[g][0], a, 0, 0, 0);
                a = __builtin_amdgcn_mfma_f32_16x16x32_bf16(zhi[1], whiF[g][1], a, 0, 0, 0);
                a = __builtin_amdgcn_mfma_f32_16x16x32_bf16(zlo[0], whiF[g][0], a, 0, 0, 0);
                a = __builtin_amdgcn_mfma_f32_16x16x32_bf16(zlo[1], whiF[g][1], a, 0, 0, 0);
                a = __builtin_amdgcn_mfma_f32_16x16x32_bf16(zhi[0], wloF[g][0], a, 0, 0, 0);
                a = __builtin_amdgcn_mfma_f32_16x16x32_bf16(zhi[1], wloF[g][1], a, 0, 0, 0);
                acc[g] = a;
            }

            // in-register LSTM update: lane has i,f,g,o for unit u, 4 batch rows
            const int u = w * 16 + lm;
            #pragma unroll
            for (int r = 0; r < 4; ++r) {
                const float gi = sigm_f(acc[0][r]);
                const float gf = sigm_f(acc[1][r]);
                const float gg = tanh_f(acc[2][r]);
                const float go = sigm_f(acc[3][r]);
                c4[r] = fmaf(gf, c4[r], gi * gg);
                const float hv = go * tanh_f(c4[r]);
                const int row = lg * 4 + r;
                const __bf16 hb = (__bf16)hv;
                hhi[row][u] = hb;
                hlo[row][u] = (__bf16)(hv - (float)hb);
            }
            // h(t) published by barrier A of next iteration
        }
        __syncthreads();   // final h published

        // ---- linear head: out[b][bin] = h[b]·lw[bin] + lb[bin] ----
        {
            const int m = tid & 15, up = tid >> 4;
            const float* lwb = lw + bin * HID;
            float s = 0.0f;
            #pragma unroll
            for (int e = 0; e < 4; ++e) {
                const int uu = up * 4 + e;
                s = fmaf((float)hhi[m][uu] + (float)hlo[m][uu], lwb[uu], s);
            }
            part[tid] = s;
            __syncthreads();
            if (tid < 16) {
                float v = lb[bin];
                #pragma unroll
                for (int j = 0; j < 16; ++j) v += part[j * 16 + tid];
                out[(size_t)(b0 + tid) * NB + bin] = v;
            }
            __syncthreads();   // before LDS reuse by next bin
        }
    }
}

extern "C" void kernel_launch(void* const* d_in, const int* in_sizes, int n_in,
                              void* d_out, int out_size, void* d_ws, size_t ws_size,
                              hipStream_t stream) {
    const float* X   = (const float*)d_in[0];
    const float* cw  = (const float*)d_in[1];
    const float* cb  = (const float*)d_in[2];
    const float* wih = (const float*)d_in[3];
    const float* whh = (const float*)d_in[4];
    const float* bih = (const float*)d_in[5];
    const float* bhh = (const float*)d_in[6];
    const float* lw  = (const float*)d_in[7];
    const float* lb  = (const float*)d_in[8];
    float* out = (float*)d_out;
    float* xc  = (float*)d_ws;   // 7,864,320 floats = 31.5 MB

    pool_conv_kernel<<<BATCH, 256, 0, stream>>>(X, cw, cb, xc);
    lstm_mfma_kernel<<<256, 256, 0, stream>>>(xc, wih, whh, bih, bhh, lw, lb, out);
}

// Round 6
// 433.161 us; speedup vs baseline: 2.9785x; 1.4604x over previous
//
#include <hip/hip_runtime.h>
#include <math.h>

#define BATCH 2048
#define CIN 14
#define LEN 2048
#define NB 4
#define HID 64
#define NEG 0.01f
#define LOG2E 1.44269504088896f

typedef __attribute__((ext_vector_type(8))) __bf16 bf16x8;
typedef __attribute__((ext_vector_type(4))) float f32x4;

// fast activations: v_exp_f32 + v_rcp_f32 (NO fp32 div sequence)
__device__ __forceinline__ float sigm_f(float x) {
    return __builtin_amdgcn_rcpf(1.0f + __builtin_amdgcn_exp2f(-LOG2E * x));
}
__device__ __forceinline__ float tanh_f(float x) {
    return fmaf(-2.0f, __builtin_amdgcn_rcpf(1.0f + __builtin_amdgcn_exp2f((2.0f * LOG2E) * x)), 1.0f);
}

// ---------------- Kernel A: pool (hierarchical) + conv1d(k=3,pad=1) + LeakyReLU ----------------
__device__ __forceinline__ void conv_bin(const float* __restrict__ P, int ldp, int T,
                                         int bin,
                                         const float* __restrict__ cw,
                                         const float* __restrict__ cb,
                                         float* __restrict__ dst, int tid)
{
    const float* w = cw + (size_t)bin * 4 * CIN * 3;
    const float b0 = cb[bin * 4 + 0];
    const float b1 = cb[bin * 4 + 1];
    const float b2 = cb[bin * 4 + 2];
    const float b3 = cb[bin * 4 + 3];
    for (int t = tid; t < T; t += 256) {
        float a0 = b0, a1 = b1, a2 = b2, a3 = b3;
        for (int ci = 0; ci < CIN; ++ci) {
            float pm = (t > 0)     ? P[ci * ldp + t - 1] : 0.0f;
            float p0 =               P[ci * ldp + t];
            float pp = (t < T - 1) ? P[ci * ldp + t + 1] : 0.0f;
            const float* w0 = w + (0 * CIN + ci) * 3;
            const float* w1 = w + (1 * CIN + ci) * 3;
            const float* w2 = w + (2 * CIN + ci) * 3;
            const float* w3 = w + (3 * CIN + ci) * 3;
            a0 += w0[0] * pm + w0[1] * p0 + w0[2] * pp;
            a1 += w1[0] * pm + w1[1] * p0 + w1[2] * pp;
            a2 += w2[0] * pm + w2[1] * p0 + w2[2] * pp;
            a3 += w3[0] * pm + w3[1] * p0 + w3[2] * pp;
        }
        a0 = (a0 >= 0.0f) ? a0 : NEG * a0;
        a1 = (a1 >= 0.0f) ? a1 : NEG * a1;
        a2 = (a2 >= 0.0f) ? a2 : NEG * a2;
        a3 = (a3 >= 0.0f) ? a3 : NEG * a3;
        *reinterpret_cast<float4*>(dst + (size_t)t * 4) = make_float4(a0, a1, a2, a3);
    }
}

__global__ __launch_bounds__(256) void pool_conv_kernel(
    const float* __restrict__ X, const float* __restrict__ cw,
    const float* __restrict__ cb, float* __restrict__ xc)
{
    __shared__ float Pa[CIN][512];
    __shared__ float Pb[CIN][256];
    const int b = blockIdx.x;
    const int tid = threadIdx.x;

    for (int idx = tid; idx < CIN * 512; idx += 256) {
        int c = idx >> 9, t = idx & 511;
        const float4 v = *reinterpret_cast<const float4*>(X + ((size_t)b * CIN + c) * LEN + 4 * t);
        Pa[c][t] = 0.25f * (v.x + v.y + v.z + v.w);
    }
    __syncthreads();

    conv_bin(&Pa[0][0], 512, 512, 0, cw, cb, xc + (size_t)b * 512 * 4, tid);
    for (int idx = tid; idx < CIN * 256; idx += 256) {
        int c = idx >> 8, t = idx & 255;
        Pb[c][t] = 0.5f * (Pa[c][2 * t] + Pa[c][2 * t + 1]);
    }
    __syncthreads();

    conv_bin(&Pb[0][0], 256, 256, 1, cw, cb, xc + 4194304 + (size_t)b * 256 * 4, tid);
    for (int idx = tid; idx < CIN * 128; idx += 256) {
        int c = idx >> 7, t = idx & 127;
        Pa[c][t] = 0.5f * (Pb[c][2 * t] + Pb[c][2 * t + 1]);
    }
    __syncthreads();

    conv_bin(&Pa[0][0], 512, 128, 2, cw, cb, xc + 6291456 + (size_t)b * 128 * 4, tid);
    for (int idx = tid; idx < CIN * 64; idx += 256) {
        int c = idx >> 6, t = idx & 63;
        Pb[c][t] = 0.5f * (Pa[c][2 * t] + Pa[c][2 * t + 1]);
    }
    __syncthreads();

    conv_bin(&Pb[0][0], 256, 64, 3, cw, cb, xc + 7340032 + (size_t)b * 64 * 4, tid);
}

// ---------------- Kernel B: MFMA LSTM scan + linear head ----------------
// 256 blocks x 256 threads (4 waves). Blocks 0..127: bin 0; 128..255: bins 1,2,3 chained.
// Per step: gates[16 b][256 cols] = 7 MFMAs/gate on the matrix pipe:
//   1 x-tile  (A = [x_hi(4)|x_lo(4)|0...], B = [Wih_hi|Wih_hi|0...])  -> exact x, W rounded
//   2 h_hi x Whh_hi, 2 h_lo x Whh_hi, 2 h_hi x Whh_lo                -> split-bf16 fp32 recurrent
// C-init = bias splat (fp32). h ping-pong LDS planes stride 80 (16B-aligned b128, 1 barrier/step).
// Activations via v_exp+v_rcp (no fp32 div). Lane holds i,f,g,o of ONE unit x 4 batch rows.

__global__ __launch_bounds__(256, 1) void lstm_mfma_kernel(
    const float* __restrict__ xc,
    const float* __restrict__ wih, const float* __restrict__ whh,
    const float* __restrict__ bih, const float* __restrict__ bhh,
    const float* __restrict__ lw, const float* __restrict__ lb,
    float* __restrict__ out)
{
    __shared__ __bf16 hbuf[2][2][16][80];   // [pingpong][hi/lo][row][unit], 160B rows (16B aligned)
    __shared__ __bf16 xbuf[16][65][8];      // [batch][step][xhi(4)|xlo(4)], 1040B batch stride
    __shared__ float  part[256];

    const int tid = threadIdx.x;
    const int w   = tid >> 6;
    const int l   = tid & 63;
    const int lm  = l & 15;
    const int lg  = l >> 4;

    const int TS[NB]     = {512, 256, 128, 64};
    const size_t OFF[NB] = {0, 4194304, 6291456, 7340032};

    const bool isBin0 = (blockIdx.x < 128);
    const int b0   = (isBin0 ? blockIdx.x : (blockIdx.x - 128)) * 16;
    const int binS = isBin0 ? 0 : 1;
    const int binE = isBin0 ? 1 : 4;

    for (int bin = binS; bin < binE; ++bin) {
        const int T = TS[bin];
        const float* xbase = xc + OFF[bin];

        // ---- weights: Whh split fragments + Wih x-tile B-frag + bias ----
        bf16x8 whiF[4][2], wloF[4][2], xwB[4];
        float  bias[4];
        #pragma unroll
        for (int g = 0; g < 4; ++g) {
            const int col = bin * 256 + g * 64 + w * 16 + lm;
            const float* wr = whh + (size_t)col * 64;
            #pragma unroll
            for (int kt = 0; kt < 2; ++kt) {
                const float* p = wr + kt * 32 + lg * 8;
                const float4 u0 = *reinterpret_cast<const float4*>(p);
                const float4 u1 = *reinterpret_cast<const float4*>(p + 4);
                const float v[8] = {u0.x, u0.y, u0.z, u0.w, u1.x, u1.y, u1.z, u1.w};
                bf16x8 hi8, lo8;
                #pragma unroll
                for (int e = 0; e < 8; ++e) {
                    const __bf16 hb = (__bf16)v[e];
                    hi8[e] = hb;
                    lo8[e] = (__bf16)(v[e] - (float)hb);
                }
                whiF[g][kt] = hi8;
                wloF[g][kt] = lo8;
            }
            const float4 wiv = *reinterpret_cast<const float4*>(wih + (size_t)col * 4);
            bf16x8 xw;
            xw[0] = (__bf16)wiv.x; xw[1] = (__bf16)wiv.y;
            xw[2] = (__bf16)wiv.z; xw[3] = (__bf16)wiv.w;
            xw[4] = xw[0]; xw[5] = xw[1]; xw[6] = xw[2]; xw[7] = xw[3];
            if (lg != 0) {
                #pragma unroll
                for (int e = 0; e < 8; ++e) xw[e] = (__bf16)0.0f;
            }
            xwB[g] = xw;
            bias[g] = bih[col] + bhh[col];
        }

        // ---- zero ping-pong buffer 0 (read at t=0) ----
        {
            __bf16* hz = &hbuf[0][0][0][0];
            #pragma unroll
            for (int i = 0; i < 10; ++i) hz[tid + i * 256] = (__bf16)0.0f;
        }
        float c4[4] = {0.0f, 0.0f, 0.0f, 0.0f};

        for (int t = 0; t < T; ++t) {
            const int tw = t & 63;
            if (tw == 0) {
                __syncthreads();   // all waves done reading previous x window
                #pragma unroll
                for (int i = 0; i < 4; ++i) {
                    const int idx = tid + i * 256;
                    const int bb = idx >> 6, s = idx & 63;
                    const float4 xv = *reinterpret_cast<const float4*>(
                        xbase + ((size_t)(b0 + bb) * T + t + s) * 4);
                    bf16x8 pk;
                    pk[0] = (__bf16)xv.x; pk[1] = (__bf16)xv.y;
                    pk[2] = (__bf16)xv.z; pk[3] = (__bf16)xv.w;
                    pk[4] = (__bf16)(xv.x - (float)pk[0]);
                    pk[5] = (__bf16)(xv.y - (float)pk[1]);
                    pk[6] = (__bf16)(xv.z - (float)pk[2]);
                    pk[7] = (__bf16)(xv.w - (float)pk[3]);
                    *reinterpret_cast<bf16x8*>(&xbuf[bb][s][0]) = pk;
                }
            }
            __syncthreads();   // h(t-1) writes + x window visible

            const int p = t & 1, q = p ^ 1;

            // A-fragments: 4 aligned b128 reads (h) + 1 for x (lg==0 lanes)
            bf16x8 zhi[2], zlo[2];
            #pragma unroll
            for (int kt = 0; kt < 2; ++kt) {
                zhi[kt] = *reinterpret_cast<const bf16x8*>(&hbuf[p][0][lm][kt * 32 + lg * 8]);
                zlo[kt] = *reinterpret_cast<const bf16x8*>(&hbuf[p][1][lm][kt * 32 + lg * 8]);
            }
            bf16x8 xf;
            #pragma unroll
            for (int e = 0; e < 8; ++e) xf[e] = (__bf16)0.0f;
            if (lg == 0) xf = *reinterpret_cast<const bf16x8*>(&xbuf[lm][tw][0]);

            // gates: bias splat + 7 MFMAs per gate
            f32x4 acc[4];
            #pragma unroll
            for (int g = 0; g < 4; ++g) {
                f32x4 a = {bias[g], bias[g], bias[g], bias[g]};
                a = __builtin_amdgcn_mfma_f32_16x16x32_bf16(xf,     xwB[g],     a, 0, 0, 0);
                a = __builtin_amdgcn_mfma_f32_16x16x32_bf16(zhi[0], whiF[g][0], a, 0, 0, 0);
                a = __builtin_amdgcn_mfma_f32_16x16x32_bf16(zhi[1], whiF[g][1], a, 0, 0, 0);
                a = __builtin_amdgcn_mfma_f32_16x16x32_bf16(zlo[0], whiF[g][0], a, 0, 0, 0);
                a = __builtin_amdgcn_mfma_f32_16x16x32_bf16(zlo[1], whiF[g][1], a, 0, 0, 0);
                a = __builtin_amdgcn_mfma_f32_16x16x32_bf16(zhi[0], wloF[g][0], a, 0, 0, 0);
                a = __builtin_amdgcn_mfma_f32_16x16x32_bf16(zhi[1], wloF[g][1], a, 0, 0, 0);
                acc[g] = a;
            }

            // in-register cell update; write h(t) to the OTHER buffer (1 barrier/step)
            const int u = w * 16 + lm;
            #pragma unroll
            for (int r = 0; r < 4; ++r) {
                const float gi = sigm_f(acc[0][r]);
                const float gf = sigm_f(acc[1][r]);
                const float gg = tanh_f(acc[2][r]);
                const float go = sigm_f(acc[3][r]);
                c4[r] = fmaf(gf, c4[r], gi * gg);
                const float hv = go * tanh_f(c4[r]);
                const int row = lg * 4 + r;
                const __bf16 hb = (__bf16)hv;
                hbuf[q][0][row][u] = hb;
                hbuf[q][1][row][u] = (__bf16)(hv - (float)hb);
            }
        }
        __syncthreads();   // final h (in hbuf[T&1 == 0]) published

        // ---- linear head ----
        {
            const int m = tid & 15, up = tid >> 4;
            const float* lwb = lw + bin * HID;
            float s = 0.0f;
            #pragma unroll
            for (int e = 0; e < 4; ++e) {
                const int uu = up * 4 + e;
                s = fmaf((float)hbuf[0][0][m][uu] + (float)hbuf[0][1][m][uu], lwb[uu], s);
            }
            part[tid] = s;
            __syncthreads();
            if (tid < 16) {
                float v = lb[bin];
                #pragma unroll
                for (int j = 0; j < 16; ++j) v += part[j * 16 + tid];
                out[(size_t)(b0 + tid) * NB + bin] = v;
            }
            __syncthreads();   // before LDS reuse by next bin
        }
    }
}

extern "C" void kernel_launch(void* const* d_in, const int* in_sizes, int n_in,
                              void* d_out, int out_size, void* d_ws, size_t ws_size,
                              hipStream_t stream) {
    const float* X   = (const float*)d_in[0];
    const float* cw  = (const float*)d_in[1];
    const float* cb  = (const float*)d_in[2];
    const float* wih = (const float*)d_in[3];
    const float* whh = (const float*)d_in[4];
    const float* bih = (const float*)d_in[5];
    const float* bhh = (const float*)d_in[6];
    const float* lw  = (const float*)d_in[7];
    const float* lb  = (const float*)d_in[8];
    float* out = (float*)d_out;
    float* xc  = (float*)d_ws;   // 7,864,320 floats = 31.5 MB

    pool_conv_kernel<<<BATCH, 256, 0, stream>>>(X, cw, cb, xc);
    lstm_mfma_kernel<<<256, 256, 0, stream>>>(xc, wih, whh, bih, bhh, lw, lb, out);
}